// Round 1
// baseline (27.694 us; speedup 1.0000x reference)
//
#include <hip/hip_runtime.h>
#include <math.h>

// Problem constants (from setup_inputs): xcorr [32, 3, 64, 4096] fp32, nlag = 2048.
#define NB 32
#define NC 3
#define NX 64
#define NT 4096
#define NROWS (NB * NC * NX)   // 6144
#define NGRID 201

__device__ __forceinline__ bool better(float va, int ia, float vb, int ib) {
    // lexicographic: larger value wins; tie -> lower index wins (lax.top_k stability)
    return (va > vb) || (va == vb && ia < ib);
}

// Phase 1: one block per row (b,c,x). Finds top-2 local maxima of |xcorr| along lag,
// does the parabolic sub-sample refinement on a 201-pt grid, writes per-row
// (weight, interpolated score, fractional index) to workspace.
__global__ __launch_bounds__(256) void row_peaks_kernel(
    const float* __restrict__ xcorr,
    float* __restrict__ w_out,     // [NROWS]
    float* __restrict__ s_out,     // [NROWS]
    float* __restrict__ f_out)     // [NROWS]
{
    __shared__ float xs[NT];
    __shared__ float rv0[4], rv1[4];
    __shared__ int   ri0[4], ri1[4];

    const int row = blockIdx.x;
    const int tid = threadIdx.x;
    const float* __restrict__ xr = xcorr + (size_t)row * NT;

    // ---- load row, take abs, stage in LDS (coalesced float4) ----
    #pragma unroll
    for (int it = 0; it < NT / 1024; ++it) {
        const int e = it * 1024 + tid * 4;
        float4 v = *reinterpret_cast<const float4*>(xr + e);
        xs[e + 0] = fabsf(v.x);
        xs[e + 1] = fabsf(v.y);
        xs[e + 2] = fabsf(v.z);
        xs[e + 3] = fabsf(v.w);
    }
    __syncthreads();

    // ---- per-thread top-2 of masked values (strided, ascending index) ----
    float v0 = -1.0f, v1 = -1.0f;
    int   i0 = 0x7fffffff, i1 = 0x7fffffff;
    #pragma unroll
    for (int it = 0; it < NT / 256; ++it) {
        const int t = it * 256 + tid;
        const float c = xs[t];
        const float l = (t > 0)      ? xs[t - 1] : -INFINITY;
        const float r = (t < NT - 1) ? xs[t + 1] : -INFINITY;
        // keep = (smax == x); v = x*keep  (zeros stay as candidates, like the ref)
        const float v = (c >= l && c >= r) ? c : 0.0f;
        if (v > v0)      { v1 = v0; i1 = i0; v0 = v; i0 = t; }
        else if (v > v1) { v1 = v;  i1 = t; }
    }

    // ---- wave butterfly top-2 merge ----
    #pragma unroll
    for (int off = 1; off < 64; off <<= 1) {
        const float ov0 = __shfl_xor(v0, off);
        const int   oi0 = __shfl_xor(i0, off);
        const float ov1 = __shfl_xor(v1, off);
        const int   oi1 = __shfl_xor(i1, off);
        if (better(ov0, oi0, v0, i0)) {
            float nv1; int ni1;
            if (better(v0, i0, ov1, oi1)) { nv1 = v0;  ni1 = i0;  }
            else                          { nv1 = ov1; ni1 = oi1; }
            v0 = ov0; i0 = oi0; v1 = nv1; i1 = ni1;
        } else {
            if (better(ov0, oi0, v1, i1)) { v1 = ov0; i1 = oi0; }
        }
    }

    const int wid = tid >> 6;
    if ((tid & 63) == 0) { rv0[wid] = v0; ri0[wid] = i0; rv1[wid] = v1; ri1[wid] = i1; }
    __syncthreads();

    // ---- wave 0: merge 4 wave results, then 201-pt grid argmax ----
    if (tid < 64) {
        float a0 = rv0[0], a1 = rv1[0];
        int   ai0 = ri0[0], ai1 = ri1[0];
        #pragma unroll
        for (int w = 1; w < 4; ++w) {
            const float b0 = rv0[w], b1 = rv1[w];
            const int   bi0 = ri0[w], bi1 = ri1[w];
            if (better(b0, bi0, a0, ai0)) {
                float nv1; int ni1;
                if (better(a0, ai0, b1, bi1)) { nv1 = a0; ni1 = ai0; }
                else                          { nv1 = b1; ni1 = bi1; }
                a0 = b0; ai0 = bi0; a1 = nv1; ai1 = ni1;
            } else {
                if (better(b0, bi0, a1, ai1)) { a1 = b0; ai1 = bi0; }
            }
        }

        const float s0 = a0, s1 = a1;
        const int   p0 = ai0;
        const float s0sq   = s0 * s0;
        const float weight = (0.1f + 3.0f * (s0 - s1)) * s0sq;

        // parabola through neighbors (indices clipped like jnp.clip)
        const int im1 = (p0 - 1 < 0) ? 0 : p0 - 1;
        const int ip1 = (p0 + 1 > NT - 1) ? NT - 1 : p0 + 1;
        const float ym1 = xs[im1], yc = xs[p0], yp1 = xs[ip1];
        const float A = 0.5f * (ym1 + yp1) - yc;
        const float B = 0.5f * (yp1 - ym1);
        const float C = yc;

        // grid argmax: yg = (A*xg + B)*xg + C, xg = linspace(-1,1,201)
        float bv = -INFINITY; int bi = 0x7fffffff;
        #pragma unroll
        for (int k = 0; k < 4; ++k) {
            const int gi = tid + k * 64;
            if (gi < NGRID) {
                const float xg = 0.01f * (float)(gi - 100);
                const float yg = (A * xg + B) * xg + C;
                if (yg > bv) { bv = yg; bi = gi; }   // strict > keeps first occurrence
            }
        }
        #pragma unroll
        for (int off = 1; off < 64; off <<= 1) {
            const float ov = __shfl_xor(bv, off);
            const int   oi = __shfl_xor(bi, off);
            if (ov > bv || (ov == bv && oi < bi)) { bv = ov; bi = oi; }
        }

        if (tid == 0) {
            const float sub = 0.01f * (float)(bi - 100);
            w_out[row] = weight;
            s_out[row] = bv;
            f_out[row] = (float)p0 + sub;
        }
    }
}

// Phase 2: per (b,x) pick the channel with max weight (first occurrence), emit
// [max_cc, weight, shift_t, shift_idx] stacked as (4, NB, 1, NX).
__global__ __launch_bounds__(256) void select_channel_kernel(
    const float* __restrict__ w_in,
    const float* __restrict__ s_in,
    const float* __restrict__ f_in,
    const int*   __restrict__ nlag_p,
    float* __restrict__ out)
{
    const int idx = blockIdx.x * blockDim.x + threadIdx.x;
    const int n = NB * NX;
    if (idx >= n) return;
    const int b = idx / NX;
    const int x = idx % NX;

    const float nlagf = (float)(*nlag_p);

    float bw = -INFINITY; int bc = 0;
    #pragma unroll
    for (int c = 0; c < NC; ++c) {
        const float wc = w_in[(b * NC + c) * NX + x];
        if (wc > bw) { bw = wc; bc = c; }   // strict > = first-occurrence argmax
    }
    const int rsel = (b * NC + bc) * NX + x;
    const float mc = s_in[rsel];
    const float shift_idx = f_in[rsel] - nlagf;

    const int o = b * NX + x;
    out[0 * n + o] = mc;
    out[1 * n + o] = bw;
    out[2 * n + o] = shift_idx / 100.0f;
    out[3 * n + o] = shift_idx;
}

extern "C" void kernel_launch(void* const* d_in, const int* in_sizes, int n_in,
                              void* d_out, int out_size, void* d_ws, size_t ws_size,
                              hipStream_t stream) {
    const float* xcorr  = (const float*)d_in[0];
    const int*   nlag_p = (const int*)d_in[1];
    float* out = (float*)d_out;

    float* ws = (float*)d_ws;
    float* w_buf = ws;              // [NROWS]
    float* s_buf = ws + NROWS;      // [NROWS]
    float* f_buf = ws + 2 * NROWS;  // [NROWS]

    row_peaks_kernel<<<NROWS, 256, 0, stream>>>(xcorr, w_buf, s_buf, f_buf);

    const int n2 = NB * NX;
    select_channel_kernel<<<(n2 + 255) / 256, 256, 0, stream>>>(
        w_buf, s_buf, f_buf, nlag_p, out);
}